// Round 1
// baseline (4657.275 us; speedup 1.0000x reference)
//
#include <hip/hip_runtime.h>

#define NTOK 32768   // B*S per tensor
#define HDIM 1024
#define H4   256
#define NLEV 4

// ---- bf16 helpers (round-to-nearest-even), avoid API version issues ----
__device__ __forceinline__ unsigned short f2bf(float f) {
  unsigned u = __float_as_uint(f);
  u += 0x7fffu + ((u >> 16) & 1u);
  return (unsigned short)(u >> 16);
}
__device__ __forceinline__ float bf2f(unsigned short h) {
  return __uint_as_float((unsigned)h << 16);
}

// =====================================================================
// Kernel 1: predictor logits.  grid (512, 4, 2), block 256.
// Block computes 64 tokens x 256 cols (one level's hidden layer) in fp32,
// then relu + dot with Pw2 -> logits[tensor][level][token].
// =====================================================================
__global__ __launch_bounds__(256) void predictor_kernel(
    const float* __restrict__ keys, const float* __restrict__ vals,
    const float* __restrict__ Pw1, const float* __restrict__ Pb1,
    const float* __restrict__ Pw2, const float* __restrict__ Pb2,
    float* __restrict__ logits)
{
  const int tid  = threadIdx.x;
  const int tile = blockIdx.x;   // 512 tiles of 64 tokens
  const int lev  = blockIdx.y;
  const int tens = blockIdx.z;
  const float* __restrict__ X = tens ? vals : keys;
  const float* __restrict__ W = Pw1 + (size_t)lev * HDIM * H4;  // [k][c] row-major

  __shared__ float Xs[32][68];    // [k][t], padded, 16B-aligned rows
  __shared__ float Ws[32][256];   // [k][c]
  __shared__ float red[64][33];   // reduction scratch, padded

  const int tokg = tid >> 5;      // 0..7  (8 tokens each)
  const int colg = tid & 31;      // 0..31 (8 cols each)

  float acc[8][8];
#pragma unroll
  for (int t = 0; t < 8; ++t)
#pragma unroll
    for (int c = 0; c < 8; ++c) acc[t][c] = 0.f;

  for (int kc = 0; kc < 32; ++kc) {   // 32 k-chunks of 32
    __syncthreads();
    // stage X chunk: 64 tokens x 32 k, transposed into Xs[k][t]
    {
      int j = tid;
      int t64 = j >> 3, kf4 = j & 7;
      float4 v = *(const float4*)&X[(size_t)(tile * 64 + t64) * HDIM + kc * 32 + kf4 * 4];
      Xs[kf4 * 4 + 0][t64] = v.x; Xs[kf4 * 4 + 1][t64] = v.y;
      Xs[kf4 * 4 + 2][t64] = v.z; Xs[kf4 * 4 + 3][t64] = v.w;
      j = tid + 256;
      t64 = j >> 3; kf4 = j & 7;
      float4 w = *(const float4*)&X[(size_t)(tile * 64 + t64) * HDIM + kc * 32 + kf4 * 4];
      Xs[kf4 * 4 + 0][t64] = w.x; Xs[kf4 * 4 + 1][t64] = w.y;
      Xs[kf4 * 4 + 2][t64] = w.z; Xs[kf4 * 4 + 3][t64] = w.w;
    }
    // stage W chunk: 32 k x 256 cols (copy, already [k][c])
#pragma unroll
    for (int s = 0; s < 8; ++s) {
      int j = tid + s * 256;
      int kr = j >> 6, cf4 = j & 63;
      *(float4*)&Ws[kr][cf4 * 4] =
          *(const float4*)&W[(size_t)(kc * 32 + kr) * H4 + cf4 * 4];
    }
    __syncthreads();
#pragma unroll 8
    for (int kk = 0; kk < 32; ++kk) {
      float4 xa = *(const float4*)&Xs[kk][tokg * 8];
      float4 xb = *(const float4*)&Xs[kk][tokg * 8 + 4];
      float4 wa = *(const float4*)&Ws[kk][colg * 8];
      float4 wb = *(const float4*)&Ws[kk][colg * 8 + 4];
      float xr[8] = {xa.x, xa.y, xa.z, xa.w, xb.x, xb.y, xb.z, xb.w};
      float wr[8] = {wa.x, wa.y, wa.z, wa.w, wb.x, wb.y, wb.z, wb.w};
#pragma unroll
      for (int t = 0; t < 8; ++t)
#pragma unroll
        for (int c = 0; c < 8; ++c)
          acc[t][c] = fmaf(xr[t], wr[c], acc[t][c]);
    }
  }

  // epilogue: bias + relu + dot with Pw2, reduce across 32 col-groups
  const float* __restrict__ b1 = Pb1 + lev * H4;
  const float* __restrict__ w2 = Pw2 + lev * H4;
  float part[8];
#pragma unroll
  for (int t = 0; t < 8; ++t) part[t] = 0.f;
#pragma unroll
  for (int c = 0; c < 8; ++c) {
    float b1c = b1[colg * 8 + c];
    float w2c = w2[colg * 8 + c];
#pragma unroll
    for (int t = 0; t < 8; ++t)
      part[t] = fmaf(fmaxf(acc[t][c] + b1c, 0.f), w2c, part[t]);
  }
  __syncthreads();
#pragma unroll
  for (int t = 0; t < 8; ++t) red[tokg * 8 + t][colg] = part[t];
  __syncthreads();
  if (tid < 64) {
    float s = Pb2[lev];
#pragma unroll
    for (int c = 0; c < 32; ++c) s += red[tid][c];
    logits[((size_t)tens * NLEV + lev) * NTOK + tile * 64 + tid] = s;
  }
}

// =====================================================================
// Kernel 2: argmax over 4 levels (first-max tiebreak) + bin by level.
// =====================================================================
__global__ __launch_bounds__(256) void argmax_kernel(
    const float* __restrict__ logits, int* __restrict__ counts,
    int* __restrict__ bins)
{
  int i = blockIdx.x * 256 + threadIdx.x;
  if (i >= 2 * NTOK) return;
  int tens = i >> 15;          // NTOK = 2^15
  int tok  = i & (NTOK - 1);
  const float* lg = logits + (size_t)tens * NLEV * NTOK;
  float best = lg[tok];
  int bl = 0;
#pragma unroll
  for (int l = 1; l < 4; ++l) {
    float v = lg[l * NTOK + tok];
    if (v > best) { best = v; bl = l; }   // strict > keeps first max
  }
  int bin = tens * 4 + bl;
  int pos = atomicAdd(&counts[bin], 1);
  bins[(size_t)bin * NTOK + pos] = tok;
}

// =====================================================================
// Kernel 3: per-bin bottleneck MLP.  grid (1024, 8), block 256.
// 16-token tiles; x staged in LDS as bf16; w1 staged in LDS fp32;
// w2 streamed coalesced from global; fp32 accumulation.
// =====================================================================
struct CompWeights {
  const float* w1[4];
  const float* b1[4];
  const float* w2[4];
  const float* b2[4];
};

__global__ __launch_bounds__(256) void compress_kernel(
    const float* __restrict__ keys, const float* __restrict__ vals,
    CompWeights cw,
    const int* __restrict__ counts, const int* __restrict__ bins,
    float* __restrict__ out)
{
  const int tid = threadIdx.x;
  const int bin = blockIdx.y;
  const int tens = bin >> 2;
  const int lev  = bin & 3;
  const int d = HDIM >> lev;
  const float* __restrict__ X  = tens ? vals : keys;
  const float* __restrict__ w1 = cw.w1[lev];
  const float* __restrict__ b1 = cw.b1[lev];
  const float* __restrict__ w2 = cw.w2[lev];
  const float* __restrict__ b2 = cw.b2[lev];
  float* __restrict__ outT = out + (size_t)tens * NTOK * HDIM;
  const int count = counts[bin];
  const int* __restrict__ mybins = bins + (size_t)bin * NTOK;

  __shared__ unsigned short XsBf[16][1024];  // 32 KB
  __shared__ float W1s[32][128];             // 16 KB
  __shared__ float Hs[16][128];              //  8 KB
  __shared__ int tokS[16];

  const int tA = tid >> 4;         // token 0..15 (phase A)
  const int jA = (tid & 15) * 8;   // hidden col base (phase A)

  for (int tile = blockIdx.x; tile * 16 < count; tile += gridDim.x) {
    __syncthreads();
    const int nt = min(16, count - tile * 16);
    if (tid < nt) tokS[tid] = mybins[tile * 16 + tid];
    __syncthreads();
    // gather X tile -> bf16 LDS
    for (int s = 0; s < nt; ++s) {
      float4 v = *(const float4*)&X[(size_t)tokS[s] * HDIM + tid * 4];
      ushort4 u;
      u.x = f2bf(v.x); u.y = f2bf(v.y); u.z = f2bf(v.z); u.w = f2bf(v.w);
      *(ushort4*)&XsBf[s][tid * 4] = u;
    }
    __syncthreads();

    float yacc[16][4];
#pragma unroll
    for (int t = 0; t < 16; ++t)
#pragma unroll
      for (int c = 0; c < 4; ++c) yacc[t][c] = 0.f;

    for (int jc = 0; jc < d; jc += 128) {
      float hacc[8];
#pragma unroll
      for (int c = 0; c < 8; ++c) hacc[c] = 0.f;

      for (int kc = 0; kc < HDIM; kc += 32) {
        __syncthreads();
        // stage w1 chunk: 32 k x 128 j
#pragma unroll
        for (int s2 = 0; s2 < 4; ++s2) {
          int j = tid + s2 * 256;
          int kr = j >> 5, c4 = j & 31;
          *(float4*)&W1s[kr][c4 * 4] =
              *(const float4*)&w1[(size_t)(kc + kr) * d + jc + c4 * 4];
        }
        __syncthreads();
#pragma unroll 8
        for (int kk = 0; kk < 32; ++kk) {
          float xv = bf2f(XsBf[tA][kc + kk]);
          float4 wa = *(const float4*)&W1s[kk][jA];
          float4 wb = *(const float4*)&W1s[kk][jA + 4];
          hacc[0] = fmaf(xv, wa.x, hacc[0]);
          hacc[1] = fmaf(xv, wa.y, hacc[1]);
          hacc[2] = fmaf(xv, wa.z, hacc[2]);
          hacc[3] = fmaf(xv, wa.w, hacc[3]);
          hacc[4] = fmaf(xv, wb.x, hacc[4]);
          hacc[5] = fmaf(xv, wb.y, hacc[5]);
          hacc[6] = fmaf(xv, wb.z, hacc[6]);
          hacc[7] = fmaf(xv, wb.w, hacc[7]);
        }
      }
      __syncthreads();
      // relu + bias -> Hs
#pragma unroll
      for (int c = 0; c < 8; ++c)
        Hs[tA][jA + c] = fmaxf(hacc[c] + b1[jc + jA + c], 0.f);
      __syncthreads();
      // phase B: y += relu(h) @ w2 chunk, w2 read coalesced from global
      for (int jj = 0; jj < 128; ++jj) {
        const float* w2row = w2 + (size_t)(jc + jj) * HDIM;
        float wv0 = w2row[tid];
        float wv1 = w2row[tid + 256];
        float wv2 = w2row[tid + 512];
        float wv3 = w2row[tid + 768];
#pragma unroll
        for (int t = 0; t < 16; ++t) {
          float hv = Hs[t][jj];
          yacc[t][0] = fmaf(hv, wv0, yacc[t][0]);
          yacc[t][1] = fmaf(hv, wv1, yacc[t][1]);
          yacc[t][2] = fmaf(hv, wv2, yacc[t][2]);
          yacc[t][3] = fmaf(hv, wv3, yacc[t][3]);
        }
      }
      __syncthreads();
    }
    // epilogue: bias + scatter (coalesced across tid)
#pragma unroll
    for (int c = 0; c < 4; ++c) {
      float bb = b2[tid + 256 * c];
      for (int t = 0; t < nt; ++t)
        outT[(size_t)tokS[t] * HDIM + tid + 256 * c] = yacc[t][c] + bb;
    }
  }
}

// =====================================================================
extern "C" void kernel_launch(void* const* d_in, const int* in_sizes, int n_in,
                              void* d_out, int out_size, void* d_ws, size_t ws_size,
                              hipStream_t stream)
{
  (void)in_sizes; (void)n_in; (void)out_size; (void)ws_size;
  const float* keys = (const float*)d_in[0];
  const float* vals = (const float*)d_in[1];
  const float* Pw1  = (const float*)d_in[2];
  const float* Pb1  = (const float*)d_in[3];
  const float* Pw2  = (const float*)d_in[4];
  const float* Pb2  = (const float*)d_in[5];
  CompWeights cw;
  for (int l = 0; l < 4; ++l) {
    cw.w1[l] = (const float*)d_in[6 + l * 4 + 0];
    cw.b1[l] = (const float*)d_in[6 + l * 4 + 1];
    cw.w2[l] = (const float*)d_in[6 + l * 4 + 2];
    cw.b2[l] = (const float*)d_in[6 + l * 4 + 3];
  }
  float* out = (float*)d_out;

  // workspace layout: logits[2][4][NTOK] f32 | counts[8] i32 | bins[8][NTOK] i32
  float* logits = (float*)d_ws;
  int* counts = (int*)((char*)d_ws + (size_t)2 * NLEV * NTOK * sizeof(float));
  int* bins = counts + 8;

  hipMemsetAsync(counts, 0, 8 * sizeof(int), stream);
  predictor_kernel<<<dim3(512, 4, 2), 256, 0, stream>>>(
      keys, vals, Pw1, Pb1, Pw2, Pb2, logits);
  argmax_kernel<<<dim3(256), 256, 0, stream>>>(logits, counts, bins);
  compress_kernel<<<dim3(1024, 8), 256, 0, stream>>>(
      keys, vals, cw, counts, bins, out);
}

// Round 2
// 2123.064 us; speedup vs baseline: 2.1937x; 2.1937x over previous
//
#include <hip/hip_runtime.h>

#define NTOK 32768   // B*S per tensor
#define MARGIN 0.08f

typedef __attribute__((ext_vector_type(8))) short bshort8;
typedef __attribute__((ext_vector_type(4))) float f32x4;

__device__ __forceinline__ unsigned short f2bf(float f) {
  unsigned u = __float_as_uint(f);
  u += 0x7fffu + ((u >> 16) & 1u);
  return (unsigned short)(u >> 16);
}
__device__ __forceinline__ float bf2f(unsigned short h) {
  return __uint_as_float((unsigned)h << 16);
}

// =====================================================================
// Transpose+convert fp32 [R][C] -> bf16 [C][R] for 12 weight matrices.
// =====================================================================
struct TrArgs {
  const float* src[12];
  unsigned short* dst[12];
  int R[12];
  int C[12];
};

__global__ __launch_bounds__(256) void convert_kernel(TrArgs ta) {
  __shared__ float t[32][33];
  const int mid = blockIdx.z;
  const int R = ta.R[mid], C = ta.C[mid];
  const int r0 = blockIdx.y * 32, c0 = blockIdx.x * 32;
  if (r0 >= R || c0 >= C) return;
  const float* __restrict__ src = ta.src[mid];
  unsigned short* __restrict__ dst = ta.dst[mid];
  const int tid = threadIdx.x;
#pragma unroll
  for (int it = 0; it < 4; ++it) {
    int r = it * 8 + (tid >> 5), c = tid & 31;
    t[r][c] = src[(size_t)(r0 + r) * C + c0 + c];
  }
  __syncthreads();
#pragma unroll
  for (int it = 0; it < 4; ++it) {
    int cc = it * 8 + (tid >> 5), rr = tid & 31;
    dst[(size_t)(c0 + cc) * R + r0 + rr] = f2bf(t[rr][cc]);
  }
}

// =====================================================================
// Unified 128x128x(K) bf16 MFMA GEMM core. 4 waves, wave tile 64x64.
// LDS tiles [128 rows][64 k] bf16, rows padded to 144 B (conflict-free
// ds_read_b128 fragment loads).
// MODE 0 = predictor hidden (+relu, dot w2 -> atomic logits)
// MODE 1 = compress L1 (gathered X rows, +b1, relu -> h bf16, packed)
// MODE 2 = compress L2 (h rows, +b2 -> scatter to out)
// =====================================================================
#define M_PRED 0
#define M_L1   1
#define M_L2   2

struct GArgs {
  const float* keys; const float* vals;
  const unsigned short* predW1T;        // [4][256][1024] bf16
  const float* Pb1; const float* Pw2;   // fp32
  float* logits;                        // [2][4][NTOK]
  const unsigned short* cw1T[4];        // [d][1024] bf16
  const unsigned short* cw2T[4];        // [1024][d] bf16
  const float* cb1[4]; const float* cb2[4];
  unsigned short* h;                    // packed bf16 hidden pool
  const int* counts; const int* bins;
  const long long* hOff;
  float* out;
};

template<int MODE>
__global__ __launch_bounds__(256) void gemm_core(GArgs ga) {
  const int tid  = threadIdx.x;
  const int lane = tid & 63;
  const int wave = tid >> 6;

  int lev, tens, tile, n0;
  if constexpr (MODE == M_PRED) {
    const int combo = blockIdx.x;       // 0..15 ; tile in z for L2/L3 reuse
    n0   = (combo & 1) * 128;
    lev  = (combo >> 1) & 3;
    tens = combo >> 3;
    tile = blockIdx.z;
  } else {
    n0   = blockIdx.x * 128;
    const int z = blockIdx.y;           // bin
    lev  = z & 3;
    tens = z >> 2;
    tile = blockIdx.z;
  }
  const int z = tens * 4 + lev;
  const int d = 1024 >> lev;

  int cnt, K;
  const unsigned short* Bt;
  if constexpr (MODE == M_PRED) {
    cnt = NTOK; K = 1024;
    Bt = ga.predW1T + ((size_t)lev * 256 + n0) * 1024;
  } else if constexpr (MODE == M_L1) {
    cnt = ga.counts[z]; K = 1024;
    if (n0 >= d) return;
    Bt = ga.cw1T[lev] + (size_t)n0 * 1024;
  } else {
    cnt = ga.counts[z]; K = d;
    Bt = ga.cw2T[lev] + (size_t)n0 * (size_t)d;
  }
  if (tile * 128 >= cnt) return;
  const int nt = min(128, cnt - tile * 128);

  __shared__ __align__(16) char smem[37376];
  // As: bytes [0, 18432), rows stride 144; Bs: [18432, 36864); tokS: [36864,...)
  int* tokS = (int*)(smem + 36864);

  if constexpr (MODE != M_PRED) {
    if (tid < 128) {
      int idx = tile * 128 + tid;
      tokS[tid] = ga.bins[(size_t)z * NTOK + ((tid < nt) ? idx : tile * 128)];
    }
  }

  const float* __restrict__ X = tens ? ga.vals : ga.keys;
  const unsigned short* hB = nullptr;
  long long hoff = 0;
  if constexpr (MODE == M_L2 || MODE == M_L1) hoff = ga.hOff[z];
  if constexpr (MODE == M_L2) hB = ga.h + hoff;

  f32x4 acc[4][4];
#pragma unroll
  for (int i = 0; i < 4; ++i)
#pragma unroll
    for (int j = 0; j < 4; ++j) acc[i][j] = (f32x4)0.f;

  const int wm = (wave & 1) * 64, wn = (wave >> 1) * 64;

  for (int kc = 0; kc < K; kc += 64) {
    __syncthreads();   // staging buffers free (also covers tokS publish)
    // ---- stage A tile: 128 rows x 64 k -> As (bf16, row stride 144 B)
    if constexpr (MODE == M_L2) {
#pragma unroll
      for (int it = 0; it < 4; ++it) {
        int r = it * 32 + (tid >> 3), c = tid & 7;
        int rg = tile * 128 + r;
        if (rg >= cnt) rg = cnt - 1;
        const unsigned short* src = hB + (size_t)rg * d + kc + c * 8;
        *(uint4*)(smem + r * 144 + c * 16) = *(const uint4*)src;
      }
    } else {
#pragma unroll
      for (int it = 0; it < 4; ++it) {
        int r = it * 32 + (tid >> 3), j = tid & 7;
        int rowid;
        if constexpr (MODE == M_PRED) rowid = tile * 128 + r;
        else rowid = tokS[r];
        const float* rp = X + (size_t)rowid * 1024 + kc + j * 4;
        float4 v0 = *(const float4*)rp;
        float4 v1 = *(const float4*)(rp + 32);
        ushort4 u0 = { f2bf(v0.x), f2bf(v0.y), f2bf(v0.z), f2bf(v0.w) };
        ushort4 u1 = { f2bf(v1.x), f2bf(v1.y), f2bf(v1.z), f2bf(v1.w) };
        char* dst = smem + r * 144 + j * 8;
        *(ushort4*)dst = u0;
        *(ushort4*)(dst + 64) = u1;
      }
    }
    // ---- stage B tile: 128 n x 64 k from [n][K] bf16 global
#pragma unroll
    for (int it = 0; it < 4; ++it) {
      int n = it * 32 + (tid >> 3), c = tid & 7;
      const unsigned short* src = Bt + (size_t)n * K + kc + c * 8;
      *(uint4*)(smem + 18432 + n * 144 + c * 16) = *(const uint4*)src;
    }
    __syncthreads();
    // ---- MFMA inner: 2 k-substeps of 32
#pragma unroll
    for (int s = 0; s < 2; ++s) {
      bshort8 af[4], bf[4];
#pragma unroll
      for (int i = 0; i < 4; ++i)
        af[i] = *(const bshort8*)(smem + (wm + i * 16 + (lane & 15)) * 144
                                       + s * 64 + (lane >> 4) * 16);
#pragma unroll
      for (int j = 0; j < 4; ++j)
        bf[j] = *(const bshort8*)(smem + 18432 + (wn + j * 16 + (lane & 15)) * 144
                                       + s * 64 + (lane >> 4) * 16);
#pragma unroll
      for (int i = 0; i < 4; ++i)
#pragma unroll
        for (int j = 0; j < 4; ++j)
          acc[i][j] = __builtin_amdgcn_mfma_f32_16x16x32_bf16(af[i], bf[j], acc[i][j], 0, 0, 0);
    }
  }
  __syncthreads();   // staging LDS now reusable by epilogues

  // ---- epilogues ----
  if constexpr (MODE == M_PRED) {
    // logit partial: sum_j relu(acc + b1[col]) * w2[col]; reduce over lane&15
    const float* b1 = ga.Pb1 + lev * 256 + n0;
    const float* w2 = ga.Pw2 + lev * 256 + n0;
    float part[4][4];
#pragma unroll
    for (int i = 0; i < 4; ++i)
#pragma unroll
      for (int r = 0; r < 4; ++r) part[i][r] = 0.f;
#pragma unroll
    for (int j = 0; j < 4; ++j) {
      int col = wn + j * 16 + (lane & 15);
      float bb = b1[col], ww = w2[col];
#pragma unroll
      for (int i = 0; i < 4; ++i)
#pragma unroll
        for (int r = 0; r < 4; ++r)
          part[i][r] = fmaf(fmaxf(acc[i][j][r] + bb, 0.f), ww, part[i][r]);
    }
#pragma unroll
    for (int m = 1; m < 16; m <<= 1)
#pragma unroll
      for (int i = 0; i < 4; ++i)
#pragma unroll
        for (int r = 0; r < 4; ++r)
          part[i][r] += __shfl_xor(part[i][r], m, 64);
    if ((lane & 15) == 0) {
      float* lg = ga.logits + (size_t)z * NTOK;
#pragma unroll
      for (int i = 0; i < 4; ++i)
#pragma unroll
        for (int r = 0; r < 4; ++r) {
          int row = tile * 128 + wm + i * 16 + (lane >> 4) * 4 + r;
          atomicAdd(&lg[row], part[i][r]);
        }
    }
  } else if constexpr (MODE == M_L1) {
    const float* b1 = ga.cb1[lev];
    unsigned short* Hs = (unsigned short*)smem;   // [128][128] bf16, 32 KB
#pragma unroll
    for (int i = 0; i < 4; ++i)
#pragma unroll
      for (int j = 0; j < 4; ++j) {
        int col = wn + j * 16 + (lane & 15);
        float bb = b1[n0 + col];
#pragma unroll
        for (int r = 0; r < 4; ++r) {
          int row = wm + i * 16 + (lane >> 4) * 4 + r;
          Hs[row * 128 + col] = f2bf(fmaxf(acc[i][j][r] + bb, 0.f));
        }
      }
    __syncthreads();
    unsigned short* hout = ga.h + hoff;
#pragma unroll
    for (int p = 0; p < 8; ++p) {
      int idx = p * 256 + tid;       // uint4 index over 128x128 bf16
      int row = idx >> 4;
      int cc  = (idx & 15) * 8;
      int rg = tile * 128 + row;
      if (rg < cnt)
        *(uint4*)(hout + (size_t)rg * d + n0 + cc) = *(const uint4*)(Hs + row * 128 + cc);
    }
  } else {   // M_L2
    const float* b2 = ga.cb2[lev];
    float* outT = ga.out + (size_t)tens * NTOK * 1024;
#pragma unroll
    for (int i = 0; i < 4; ++i)
#pragma unroll
      for (int r = 0; r < 4; ++r) {
        int row = wm + i * 16 + (lane >> 4) * 4 + r;
        if (row < nt) {
          int tok = tokS[row];
#pragma unroll
          for (int j = 0; j < 4; ++j) {
            int col = n0 + wn + j * 16 + (lane & 15);
            outT[(size_t)tok * 1024 + col] = acc[i][j][r] + b2[col];
          }
        }
      }
  }
}

// =====================================================================
// argmax over bf16-accuracy logits with margin; near-ties -> recheck list
// =====================================================================
__global__ __launch_bounds__(256) void argmax_margin_kernel(
    const float* __restrict__ logits, const float* __restrict__ Pb2,
    int* __restrict__ counts, int* __restrict__ bins,
    int* __restrict__ rcnt, int* __restrict__ rlist) {
  int i = blockIdx.x * 256 + threadIdx.x;
  if (i >= 2 * NTOK) return;
  int tens = i >> 15;
  int tok  = i & (NTOK - 1);
  const float* lg = logits + (size_t)tens * 4 * NTOK;
  float best = lg[tok] + Pb2[0];
  int bl = 0;
  float sec = -3.4e38f;
#pragma unroll
  for (int l = 1; l < 4; ++l) {
    float v = lg[(size_t)l * NTOK + tok] + Pb2[l];
    if (v > best) { sec = best; best = v; bl = l; }
    else if (v > sec) sec = v;
  }
  if (best - sec < MARGIN) {
    int pos = atomicAdd(&rcnt[tens], 1);
    rlist[tens * NTOK + pos] = tok;
  } else {
    int bin = tens * 4 + bl;
    int pos = atomicAdd(&counts[bin], 1);
    bins[(size_t)bin * NTOK + pos] = tok;
  }
}

// =====================================================================
// fp32 recheck GEMM: exact round-1 predictor arithmetic on gathered tokens.
// grid (32, 4, 2), block 256; 64-token tiles.
// =====================================================================
__global__ __launch_bounds__(256) void recheck_gemm(
    const float* __restrict__ keys, const float* __restrict__ vals,
    const float* __restrict__ Pw1, const float* __restrict__ Pb1,
    const float* __restrict__ Pw2, const float* __restrict__ Pb2,
    const int* __restrict__ rcnt, const int* __restrict__ rlist,
    float* __restrict__ logitsR) {
  const int tid  = threadIdx.x;
  const int lev  = blockIdx.y;
  const int tens = blockIdx.z;
  const int cnt  = rcnt[tens];
  const float* __restrict__ X = tens ? vals : keys;
  const float* __restrict__ W = Pw1 + (size_t)lev * 1024 * 256;

  __shared__ float Xs[32][68];
  __shared__ float Ws[32][256];
  __shared__ float red[64][33];
  __shared__ int tokS[64];

  const int tokg = tid >> 5;
  const int colg = tid & 31;

  for (int tile = blockIdx.x; tile * 64 < cnt; tile += gridDim.x) {
    __syncthreads();
    if (tid < 64) {
      int s = tile * 64 + tid;
      tokS[tid] = rlist[tens * NTOK + min(s, cnt - 1)];
    }
    __syncthreads();

    float acc[8][8];
#pragma unroll
    for (int t = 0; t < 8; ++t)
#pragma unroll
      for (int c = 0; c < 8; ++c) acc[t][c] = 0.f;

    for (int kc = 0; kc < 32; ++kc) {
      __syncthreads();
      {
        int j = tid;
        int t64 = j >> 3, kf4 = j & 7;
        float4 v = *(const float4*)&X[(size_t)tokS[t64] * 1024 + kc * 32 + kf4 * 4];
        Xs[kf4 * 4 + 0][t64] = v.x; Xs[kf4 * 4 + 1][t64] = v.y;
        Xs[kf4 * 4 + 2][t64] = v.z; Xs[kf4 * 4 + 3][t64] = v.w;
        j = tid + 256;
        t64 = j >> 3; kf4 = j & 7;
        float4 w = *(const float4*)&X[(size_t)tokS[t64] * 1024 + kc * 32 + kf4 * 4];
        Xs[kf4 * 4 + 0][t64] = w.x; Xs[kf4 * 4 + 1][t64] = w.y;
        Xs[kf4 * 4 + 2][t64] = w.z; Xs[kf4 * 4 + 3][t64] = w.w;
      }
#pragma unroll
      for (int s = 0; s < 8; ++s) {
        int j = tid + s * 256;
        int kr = j >> 6, cf4 = j & 63;
        *(float4*)&Ws[kr][cf4 * 4] =
            *(const float4*)&W[(size_t)(kc * 32 + kr) * 256 + cf4 * 4];
      }
      __syncthreads();
#pragma unroll 8
      for (int kk = 0; kk < 32; ++kk) {
        float4 xa = *(const float4*)&Xs[kk][tokg * 8];
        float4 xb = *(const float4*)&Xs[kk][tokg * 8 + 4];
        float4 wa = *(const float4*)&Ws[kk][colg * 8];
        float4 wb = *(const float4*)&Ws[kk][colg * 8 + 4];
        float xr[8] = {xa.x, xa.y, xa.z, xa.w, xb.x, xb.y, xb.z, xb.w};
        float wr[8] = {wa.x, wa.y, wa.z, wa.w, wb.x, wb.y, wb.z, wb.w};
#pragma unroll
        for (int t = 0; t < 8; ++t)
#pragma unroll
          for (int c = 0; c < 8; ++c)
            acc[t][c] = fmaf(xr[t], wr[c], acc[t][c]);
      }
    }

    const float* b1 = Pb1 + lev * 256;
    const float* w2 = Pw2 + lev * 256;
    float part[8];
#pragma unroll
    for (int t = 0; t < 8; ++t) part[t] = 0.f;
#pragma unroll
    for (int c = 0; c < 8; ++c) {
      float b1c = b1[colg * 8 + c];
      float w2c = w2[colg * 8 + c];
#pragma unroll
      for (int t = 0; t < 8; ++t)
        part[t] = fmaf(fmaxf(acc[t][c] + b1c, 0.f), w2c, part[t]);
    }
    __syncthreads();
#pragma unroll
    for (int t = 0; t < 8; ++t) red[tokg * 8 + t][colg] = part[t];
    __syncthreads();
    if (tid < 64 && tile * 64 + tid < cnt) {
      float s = Pb2[lev];
#pragma unroll
      for (int c = 0; c < 32; ++c) s += red[tid][c];
      logitsR[((size_t)tens * 4 + lev) * NTOK + tile * 64 + tid] = s;
    }
  }
}

__global__ __launch_bounds__(256) void recheck_argmax_kernel(
    const float* __restrict__ logitsR, const int* __restrict__ rcnt,
    const int* __restrict__ rlist, int* __restrict__ counts,
    int* __restrict__ bins) {
  int i = blockIdx.x * 256 + threadIdx.x;
  if (i >= 2 * NTOK) return;
  int tens = i >> 15;
  int slot = i & (NTOK - 1);
  if (slot >= rcnt[tens]) return;
  const float* lg = logitsR + (size_t)tens * 4 * NTOK;
  float best = lg[slot];
  int bl = 0;
#pragma unroll
  for (int l = 1; l < 4; ++l) {
    float v = lg[(size_t)l * NTOK + slot];
    if (v > best) { best = v; bl = l; }
  }
  int tok = rlist[tens * NTOK + slot];
  int bin = tens * 4 + bl;
  int pos = atomicAdd(&counts[bin], 1);
  bins[(size_t)bin * NTOK + pos] = tok;
}

__global__ void hoff_kernel(const int* __restrict__ counts,
                            long long* __restrict__ hOff) {
  long long off = 0;
  for (int b = 0; b < 8; ++b) {
    hOff[b] = off;
    off += (long long)counts[b] * (1024 >> (b & 3));
  }
}

// =====================================================================
extern "C" void kernel_launch(void* const* d_in, const int* in_sizes, int n_in,
                              void* d_out, int out_size, void* d_ws, size_t ws_size,
                              hipStream_t stream) {
  (void)in_sizes; (void)n_in; (void)out_size; (void)ws_size;
  const float* keys = (const float*)d_in[0];
  const float* vals = (const float*)d_in[1];
  const float* Pw1  = (const float*)d_in[2];
  const float* Pb1  = (const float*)d_in[3];
  const float* Pw2  = (const float*)d_in[4];
  const float* Pb2  = (const float*)d_in[5];

  char* base = (char*)d_ws;
  float* logits   = (float*)(base + 0);                 // 1 MB
  float* logitsR  = (float*)(base + 1048576);           // 1 MB
  int*   bins     = (int*)(base + 2097152);             // 1 MB
  int*   rlist    = (int*)(base + 3145728);             // 256 KB
  int*   counts   = (int*)(base + 3407872);             // 8 ints
  int*   rcnt     = (int*)(base + 3407872 + 32);        // 2 ints
  long long* hOff = (long long*)(base + 3407936);       // 8 int64
  unsigned short* predW1T = (unsigned short*)(base + 3408384);   // 2 MB
  unsigned short* cw1T0 = (unsigned short*)(base + 5505536);
  unsigned short* cw1T1 = (unsigned short*)(base + 7602688);
  unsigned short* cw1T2 = (unsigned short*)(base + 8651264);
  unsigned short* cw1T3 = (unsigned short*)(base + 9175552);
  unsigned short* cw2T0 = (unsigned short*)(base + 9437696);
  unsigned short* cw2T1 = (unsigned short*)(base + 11534848);
  unsigned short* cw2T2 = (unsigned short*)(base + 12583424);
  unsigned short* cw2T3 = (unsigned short*)(base + 13107712);
  unsigned short* hpool = (unsigned short*)(base + 13369856);

  // ---- zero logits + counters
  hipMemsetAsync(logits, 0, 1048576, stream);
  hipMemsetAsync(counts, 0, 64, stream);

  // ---- weight convert/transpose
  TrArgs ta;
  unsigned short* cw1T[4] = {cw1T0, cw1T1, cw1T2, cw1T3};
  unsigned short* cw2T[4] = {cw2T0, cw2T1, cw2T2, cw2T3};
  for (int l = 0; l < 4; ++l) {
    int d = 1024 >> l;
    ta.src[l] = Pw1 + (size_t)l * 1024 * 256;  ta.dst[l] = predW1T + (size_t)l * 256 * 1024;
    ta.R[l] = 1024; ta.C[l] = 256;
    ta.src[4 + l] = (const float*)d_in[6 + l * 4 + 0];  ta.dst[4 + l] = cw1T[l];
    ta.R[4 + l] = 1024; ta.C[4 + l] = d;
    ta.src[8 + l] = (const float*)d_in[6 + l * 4 + 2];  ta.dst[8 + l] = cw2T[l];
    ta.R[8 + l] = d; ta.C[8 + l] = 1024;
  }
  convert_kernel<<<dim3(32, 32, 12), 256, 0, stream>>>(ta);

  // ---- GEMM args
  GArgs ga;
  ga.keys = keys; ga.vals = vals;
  ga.predW1T = predW1T; ga.Pb1 = Pb1; ga.Pw2 = Pw2;
  ga.logits = logits;
  for (int l = 0; l < 4; ++l) {
    ga.cw1T[l] = cw1T[l];
    ga.cw2T[l] = cw2T[l];
    ga.cb1[l] = (const float*)d_in[6 + l * 4 + 1];
    ga.cb2[l] = (const float*)d_in[6 + l * 4 + 3];
  }
  ga.h = hpool; ga.counts = counts; ga.bins = bins; ga.hOff = hOff;
  ga.out = (float*)d_out;

  // ---- predictor (bf16 MFMA) -> logits
  gemm_core<M_PRED><<<dim3(16, 1, 256), 256, 0, stream>>>(ga);
  // ---- argmax with margin; near-ties to recheck list
  argmax_margin_kernel<<<dim3(256), 256, 0, stream>>>(logits, Pb2, counts, bins, rcnt, rlist);
  // ---- fp32 recheck of flagged tokens + re-bin
  recheck_gemm<<<dim3(32, 4, 2), 256, 0, stream>>>(keys, vals, Pw1, Pb1, Pw2, Pb2,
                                                   rcnt, rlist, logitsR);
  recheck_argmax_kernel<<<dim3(256), 256, 0, stream>>>(logitsR, rcnt, rlist, counts, bins);
  // ---- h pool offsets
  hoff_kernel<<<1, 1, 0, stream>>>(counts, hOff);
  // ---- compress: L1 then L2 (bf16 MFMA)
  gemm_core<M_L1><<<dim3(8, 8, 256), 256, 0, stream>>>(ga);
  gemm_core<M_L2><<<dim3(8, 8, 256), 256, 0, stream>>>(ga);
}